// Round 1
// baseline (2968.763 us; speedup 1.0000x reference)
//
#include <hip/hip_runtime.h>
#include <math.h>

#define WSZ 7
#define NTOK 49
#define NP 52            // tokens padded to multiple of 4
#define NH 12
#define DIM 384
#define HD 32
#define SCALE 0.1767766952966369f

// ---------------------------------------------------------------------------
// Kernel A: per-window fused qkv + attention. Writes attn output (pre-proj)
// to d_out at the FINAL window-reversed position, as [B,H,W,384].
// grid = 1024 (one block per window), block = 512 threads (8 waves).
// ---------------------------------------------------------------------------
__global__ __launch_bounds__(512) void wmsa_attn_kernel(
    const float* __restrict__ x, const float* __restrict__ qkv_w,
    const float* __restrict__ qkv_b, const float* __restrict__ rel_table,
    float* __restrict__ out)
{
    __shared__ float xs[NP][388];   // x window, rows 49..51 zeroed   (80.7 KB)
    __shared__ float wt[96][68];    // w tile transposed [col][k]     (26.1 KB)
    __shared__ float qs[NP][36];    // q (scaled)                     ( 7.5 KB)
    __shared__ float ks[NP][36];    // k                              ( 7.5 KB)
    __shared__ float vst[HD][56];   // v transposed [d][token]        ( 7.2 KB)
    __shared__ float at[NP][56];    // scores / attn probs            (11.6 KB)

    const int wi  = blockIdx.x;
    const int bi  = wi >> 6;
    const int win = wi & 63;
    const int wy  = win >> 3, wx = win & 7;
    const int tid = threadIdx.x;

    // ---- stage x window into LDS (float4), zero pad rows ----
    for (int i = tid; i < NP * 96; i += 512) {
        int n = i / 96, c4 = i % 96;
        float4 v = make_float4(0.f, 0.f, 0.f, 0.f);
        if (n < NTOK) {
            int Y = wy * 7 + n / 7, X = wx * 7 + n % 7;
            const float4* src = reinterpret_cast<const float4*>(
                x + ((size_t)((bi * 56 + Y) * 56 + X)) * DIM);
            v = src[c4];
        }
        *reinterpret_cast<float4*>(&xs[n][c4 * 4]) = v;
    }

    const int tn = tid >> 5;        // 0..15 (active: 0..12)
    const int tj = tid & 31;        // 0..31
    const bool qact = tid < 416;    // 13*32 threads for qkv GEMM

    for (int h = 0; h < NH; ++h) {
        // ---- qkv GEMM: [52,384] x [384,96] -> q|k|v, 4x3 register tile ----
        float acc[4][3];
        #pragma unroll
        for (int i = 0; i < 4; ++i)
            #pragma unroll
            for (int j = 0; j < 3; ++j) acc[i][j] = 0.f;

        for (int kt = 0; kt < 6; ++kt) {
            __syncthreads();                 // prior readers of wt/at/vst done
            // stage transposed weight tile wt[m*32+d][c], c = k within tile
            {
                int d = tid & 31, g = tid >> 5;          // g: 0..15
                #pragma unroll
                for (int r = 0; r < 12; ++r) {
                    int pair = g + r * 16;               // 0..191 -> (m,c)
                    int m = pair >> 6, c = pair & 63;
                    wt[m * 32 + d][c] =
                        qkv_w[(size_t)(kt * 64 + c) * 1152 + m * 384 + h * 32 + d];
                }
            }
            __syncthreads();
            if (qact) {
                const int n0 = tn * 4, j0 = tj * 3;
                #pragma unroll 4
                for (int kk = 0; kk < 64; kk += 4) {
                    float4 xa[4], wb[3];
                    #pragma unroll
                    for (int i = 0; i < 4; ++i)
                        xa[i] = *reinterpret_cast<const float4*>(&xs[n0 + i][kt * 64 + kk]);
                    #pragma unroll
                    for (int j = 0; j < 3; ++j)
                        wb[j] = *reinterpret_cast<const float4*>(&wt[j0 + j][kk]);
                    #pragma unroll
                    for (int i = 0; i < 4; ++i)
                        #pragma unroll
                        for (int j = 0; j < 3; ++j)
                            acc[i][j] += xa[i].x * wb[j].x + xa[i].y * wb[j].y +
                                         xa[i].z * wb[j].z + xa[i].w * wb[j].w;
                }
            }
        }
        // ---- write q (scaled, with bias), k, v^T into LDS ----
        if (qact) {
            const int n0 = tn * 4, j0 = tj * 3;
            #pragma unroll
            for (int i = 0; i < 4; ++i) {
                int n = n0 + i;
                #pragma unroll
                for (int j = 0; j < 3; ++j) {
                    int jj = j0 + j, m = jj >> 5, d = jj & 31;
                    float v = acc[i][j] + qkv_b[m * 384 + h * 32 + d];
                    if (m == 0)      qs[n][d]  = v * SCALE;
                    else if (m == 1) ks[n][d]  = v;
                    else             vst[d][n] = v;
                }
            }
        }
        __syncthreads();

        // ---- S = q k^T : [52,32]x[32,52], 2x4 tiles over 338 threads ----
        if (tid < 338) {
            int tn2 = tid / 13, tm2 = tid % 13;
            int n0 = tn2 * 2, m0 = tm2 * 4;
            float s[2][4] = {};
            #pragma unroll
            for (int k = 0; k < HD; k += 4) {
                float4 qa[2], kb[4];
                #pragma unroll
                for (int i = 0; i < 2; ++i)
                    qa[i] = *reinterpret_cast<const float4*>(&qs[n0 + i][k]);
                #pragma unroll
                for (int j = 0; j < 4; ++j)
                    kb[j] = *reinterpret_cast<const float4*>(&ks[m0 + j][k]);
                #pragma unroll
                for (int i = 0; i < 2; ++i)
                    #pragma unroll
                    for (int j = 0; j < 4; ++j)
                        s[i][j] += qa[i].x * kb[j].x + qa[i].y * kb[j].y +
                                   qa[i].z * kb[j].z + qa[i].w * kb[j].w;
            }
            #pragma unroll
            for (int i = 0; i < 2; ++i)
                #pragma unroll
                for (int j = 0; j < 4; ++j)
                    at[n0 + i][m0 + j] = s[i][j];
        }
        __syncthreads();

        // ---- softmax per row (wave per row) + bias AFTER softmax ----
        {
            int wv = tid >> 6, lane = tid & 63;
            for (int r = wv; r < NTOK; r += 8) {
                float v = (lane < NTOK) ? at[r][lane] : -3.4e38f;
                float m = v;
                #pragma unroll
                for (int off = 32; off; off >>= 1) m = fmaxf(m, __shfl_xor(m, off));
                float e = (lane < NTOK) ? __expf(v - m) : 0.f;
                float ssum = e;
                #pragma unroll
                for (int off = 32; off; off >>= 1) ssum += __shfl_xor(ssum, off);
                if (lane < NP) {
                    float res = 0.f;
                    if (lane < NTOK) {
                        int py = r / 7, px = r % 7, qy = lane / 7, qx = lane % 7;
                        int bidx = (py - qy + 6) * 13 + (px - qx + 6);
                        res = e / ssum + rel_table[bidx * NH + h];
                    }
                    at[r][lane] = res;    // pad cols 49..51 -> 0
                }
            }
        }
        __syncthreads();

        // ---- out_h = attn @ v : [49,52]x[52,32], 4x2 tiles, 208 threads ----
        if (tid < 208) {
            int tn3 = tid / 16, td = tid % 16;
            int n0 = tn3 * 4, d0 = td * 2;
            float o[4][2] = {};
            #pragma unroll
            for (int m = 0; m < NP; m += 4) {
                float4 pa[4], vb[2];
                #pragma unroll
                for (int i = 0; i < 4; ++i)
                    pa[i] = *reinterpret_cast<const float4*>(&at[n0 + i][m]);
                #pragma unroll
                for (int j = 0; j < 2; ++j)
                    vb[j] = *reinterpret_cast<const float4*>(&vst[d0 + j][m]);
                #pragma unroll
                for (int i = 0; i < 4; ++i)
                    #pragma unroll
                    for (int j = 0; j < 2; ++j)
                        o[i][j] += pa[i].x * vb[j].x + pa[i].y * vb[j].y +
                                   pa[i].z * vb[j].z + pa[i].w * vb[j].w;
            }
            #pragma unroll
            for (int i = 0; i < 4; ++i) {
                int n = n0 + i;
                if (n < NTOK) {
                    int Y = wy * 7 + n / 7, X = wx * 7 + n % 7;
                    size_t base = (size_t)((bi * 56 + Y) * 56 + X) * DIM + h * 32 + d0;
                    out[base]     = o[i][0];
                    out[base + 1] = o[i][1];
                }
            }
        }
        __syncthreads();   // end of head: at/vst/qs/ks reads complete
    }
}

// ---------------------------------------------------------------------------
// Kernel B: output projection, IN PLACE on d_out (per-token GEMV, no cross-
// token deps). grid = 50176/16 = 3136 blocks, block = 384 threads.
// Each thread owns one output column for 16 tokens.
// ---------------------------------------------------------------------------
__global__ __launch_bounds__(384) void wmsa_proj_kernel(
    const float* __restrict__ proj_w, const float* __restrict__ proj_b,
    float* __restrict__ out)
{
    __shared__ float ts[16][388];
    const int tid = threadIdx.x;                 // = output column
    const size_t tok0 = (size_t)blockIdx.x * 16;

    for (int i = tid; i < 16 * 96; i += 384) {
        int t = i / 96, c4 = i % 96;
        *reinterpret_cast<float4*>(&ts[t][c4 * 4]) =
            reinterpret_cast<const float4*>(out + (tok0 + t) * DIM)[c4];
    }
    __syncthreads();

    float acc[16];
    float b = proj_b[tid];
    #pragma unroll
    for (int t = 0; t < 16; ++t) acc[t] = b;

    for (int c = 0; c < DIM; c += 4) {
        float w0 = proj_w[(size_t)c * DIM + tid];
        float w1 = proj_w[(size_t)(c + 1) * DIM + tid];
        float w2 = proj_w[(size_t)(c + 2) * DIM + tid];
        float w3 = proj_w[(size_t)(c + 3) * DIM + tid];
        #pragma unroll
        for (int t = 0; t < 16; ++t) {
            float4 xv = *reinterpret_cast<const float4*>(&ts[t][c]);
            acc[t] += xv.x * w0 + xv.y * w1 + xv.z * w2 + xv.w * w3;
        }
    }
    #pragma unroll
    for (int t = 0; t < 16; ++t)
        out[(tok0 + t) * DIM + tid] = acc[t];
}

extern "C" void kernel_launch(void* const* d_in, const int* in_sizes, int n_in,
                              void* d_out, int out_size, void* d_ws, size_t ws_size,
                              hipStream_t stream) {
    const float* x         = (const float*)d_in[0];
    const float* qkv_w     = (const float*)d_in[1];
    const float* qkv_b     = (const float*)d_in[2];
    const float* proj_w    = (const float*)d_in[3];
    const float* proj_b    = (const float*)d_in[4];
    const float* rel_table = (const float*)d_in[5];
    float* out = (float*)d_out;

    hipLaunchKernelGGL(wmsa_attn_kernel, dim3(1024), dim3(512), 0, stream,
                       x, qkv_w, qkv_b, rel_table, out);
    hipLaunchKernelGGL(wmsa_proj_kernel, dim3(3136), dim3(384), 0, stream,
                       proj_w, proj_b, out);
}

// Round 2
// 1929.089 us; speedup vs baseline: 1.5389x; 1.5389x over previous
//
#include <hip/hip_runtime.h>
#include <math.h>

typedef unsigned short u16;
typedef __attribute__((ext_vector_type(8))) short bf16x8;
typedef __attribute__((ext_vector_type(4))) float f32x4;

#define NTOK 49
#define NP 52
#define NH 12
#define DIM 384
#define SCALE 0.1767766952966369f

// split fp32 -> bf16 hi + bf16 lo (RNE), x ≈ hi + lo with ~2^-17 rel err
__device__ __forceinline__ void split2(float x, u16& h, u16& l) {
    union { float f; unsigned u; } a; a.f = x;
    unsigned r = a.u + 0x7FFFu + ((a.u >> 16) & 1u);
    h = (u16)(r >> 16);
    union { unsigned u; float f; } b; b.u = (unsigned)h << 16;
    a.f = x - b.f;
    r = a.u + 0x7FFFu + ((a.u >> 16) & 1u);
    l = (u16)(r >> 16);
}

// ---------------------------------------------------------------------------
// Kernel A: per-window. QKV via split-bf16 MFMA, attention via fp32 VALU.
// Writes pre-proj attn output window-reversed into d_out [B,H,W,384].
// grid=1024, block=512 (8 waves: wave_m 0..3 x wave_n 0..1).
// ---------------------------------------------------------------------------
__global__ __launch_bounds__(512) void wmsa_attn_kernel(
    const float* __restrict__ x, const float* __restrict__ qkv_w,
    const float* __restrict__ qkv_b, const float* __restrict__ rel_table,
    float* __restrict__ out)
{
    __shared__ __align__(16) u16 xs_hi[64][392];     // 50176 B
    __shared__ __align__(16) u16 xs_lo[64][392];     // 50176 B
    __shared__ __align__(16) u16 bt_hi[2][96][40];   // 15360 B (dbuf)
    __shared__ __align__(16) u16 bt_lo[2][96][40];   // 15360 B
    __shared__ __align__(16) float qs[NP][36];       //  7488 B
    __shared__ __align__(16) float kss[NP][36];      //  7488 B
    __shared__ __align__(16) float vst[32][52];      //  6656 B
    __shared__ __align__(16) float at[NP][52];       // 10816 B  => 163520 B

    const int wi = blockIdx.x, bi = wi >> 6, win = wi & 63;
    const int wy = win >> 3, wx = win & 7;
    const int tid = threadIdx.x;
    const int lane = tid & 63, wv = tid >> 6;
    const int wm = wv >> 1, wn = wv & 1;

    // ---- phase 0: stage x window -> hi/lo bf16 (rows 49..63 zero) ----
    for (int i = tid; i < 64 * 96; i += 512) {
        int n = i / 96, c4 = i % 96;
        float4 v = make_float4(0.f, 0.f, 0.f, 0.f);
        if (n < NTOK) {
            int Y = wy * 7 + n / 7, X = wx * 7 + n % 7;
            v = reinterpret_cast<const float4*>(
                    x + (size_t)((bi * 56 + Y) * 56 + X) * DIM)[c4];
        }
        u16 h0,l0,h1,l1,h2,l2,h3,l3;
        split2(v.x,h0,l0); split2(v.y,h1,l1); split2(v.z,h2,l2); split2(v.w,h3,l3);
        int c = c4 * 4;
        xs_hi[n][c]=h0; xs_hi[n][c+1]=h1; xs_hi[n][c+2]=h2; xs_hi[n][c+3]=h3;
        xs_lo[n][c]=l0; xs_lo[n][c+1]=l1; xs_lo[n][c+2]=l2; xs_lo[n][c+3]=l3;
    }

    const int arow = wm * 16 + (lane & 15);
    const int koff = (lane >> 4) * 8;

    // chunk f4-index decode: f in [0,768): kl=f/24 (k-row), c4=f%24 (col/4)
    float4 r0, r1;

    for (int h = 0; h < NH; ++h) {
        f32x4 acc[3];
        #pragma unroll
        for (int f = 0; f < 3; ++f) { acc[f][0]=0.f; acc[f][1]=0.f; acc[f][2]=0.f; acc[f][3]=0.f; }

        // ---- prologue: load + store weight chunk ks=0 into buf0 ----
        {
            int kl = tid / 24, c4 = tid % 24;
            int m = c4 >> 3, d0 = (c4 & 7) * 4;
            r0 = reinterpret_cast<const float4*>(
                     qkv_w + (size_t)kl * 1152 + m * 384 + h * 32 + d0)[0];
            if (tid < 256) {
                int f1 = tid + 512; int kl1 = f1 / 24, c41 = f1 % 24;
                int m1 = c41 >> 3, d1 = (c41 & 7) * 4;
                r1 = reinterpret_cast<const float4*>(
                         qkv_w + (size_t)kl1 * 1152 + m1 * 384 + h * 32 + d1)[0];
            }
            u16 hh, ll; int n0 = c4 * 4;
            split2(r0.x,hh,ll); bt_hi[0][n0  ][kl]=hh; bt_lo[0][n0  ][kl]=ll;
            split2(r0.y,hh,ll); bt_hi[0][n0+1][kl]=hh; bt_lo[0][n0+1][kl]=ll;
            split2(r0.z,hh,ll); bt_hi[0][n0+2][kl]=hh; bt_lo[0][n0+2][kl]=ll;
            split2(r0.w,hh,ll); bt_hi[0][n0+3][kl]=hh; bt_lo[0][n0+3][kl]=ll;
            if (tid < 256) {
                int f1 = tid + 512; int kl1 = f1 / 24, c41 = f1 % 24, n1 = c41 * 4;
                split2(r1.x,hh,ll); bt_hi[0][n1  ][kl1]=hh; bt_lo[0][n1  ][kl1]=ll;
                split2(r1.y,hh,ll); bt_hi[0][n1+1][kl1]=hh; bt_lo[0][n1+1][kl1]=ll;
                split2(r1.z,hh,ll); bt_hi[0][n1+2][kl1]=hh; bt_lo[0][n1+2][kl1]=ll;
                split2(r1.w,hh,ll); bt_hi[0][n1+3][kl1]=hh; bt_lo[0][n1+3][kl1]=ll;
            }
        }
        __syncthreads();

        // ---- K-loop: 12 chunks of 32, double-buffered, T14 split ----
        for (int ksi = 0; ksi < 12; ++ksi) {
            int buf = ksi & 1;
            if (ksi < 11) {   // issue next-chunk global loads early
                int kg = (ksi + 1) * 32;
                int kl = tid / 24, c4 = tid % 24;
                int m = c4 >> 3, d0 = (c4 & 7) * 4;
                r0 = reinterpret_cast<const float4*>(
                         qkv_w + (size_t)(kg + kl) * 1152 + m * 384 + h * 32 + d0)[0];
                if (tid < 256) {
                    int f1 = tid + 512; int kl1 = f1 / 24, c41 = f1 % 24;
                    int m1 = c41 >> 3, d1 = (c41 & 7) * 4;
                    r1 = reinterpret_cast<const float4*>(
                             qkv_w + (size_t)(kg + kl1) * 1152 + m1 * 384 + h * 32 + d1)[0];
                }
            }
            bf16x8 ah = *reinterpret_cast<const bf16x8*>(&xs_hi[arow][ksi * 32 + koff]);
            bf16x8 al = *reinterpret_cast<const bf16x8*>(&xs_lo[arow][ksi * 32 + koff]);
            #pragma unroll
            for (int f = 0; f < 3; ++f) {
                int n = wn * 48 + f * 16 + (lane & 15);
                bf16x8 bh = *reinterpret_cast<const bf16x8*>(&bt_hi[buf][n][koff]);
                bf16x8 bl = *reinterpret_cast<const bf16x8*>(&bt_lo[buf][n][koff]);
                acc[f] = __builtin_amdgcn_mfma_f32_16x16x32_bf16(ah, bh, acc[f], 0, 0, 0);
                acc[f] = __builtin_amdgcn_mfma_f32_16x16x32_bf16(ah, bl, acc[f], 0, 0, 0);
                acc[f] = __builtin_amdgcn_mfma_f32_16x16x32_bf16(al, bh, acc[f], 0, 0, 0);
            }
            if (ksi < 11) {   // write-late into other buffer
                int nb = buf ^ 1;
                u16 hh, ll; int kl = tid / 24, c4 = tid % 24, n0 = c4 * 4;
                split2(r0.x,hh,ll); bt_hi[nb][n0  ][kl]=hh; bt_lo[nb][n0  ][kl]=ll;
                split2(r0.y,hh,ll); bt_hi[nb][n0+1][kl]=hh; bt_lo[nb][n0+1][kl]=ll;
                split2(r0.z,hh,ll); bt_hi[nb][n0+2][kl]=hh; bt_lo[nb][n0+2][kl]=ll;
                split2(r0.w,hh,ll); bt_hi[nb][n0+3][kl]=hh; bt_lo[nb][n0+3][kl]=ll;
                if (tid < 256) {
                    int f1 = tid + 512; int kl1 = f1 / 24, c41 = f1 % 24, n1 = c41 * 4;
                    split2(r1.x,hh,ll); bt_hi[nb][n1  ][kl1]=hh; bt_lo[nb][n1  ][kl1]=ll;
                    split2(r1.y,hh,ll); bt_hi[nb][n1+1][kl1]=hh; bt_lo[nb][n1+1][kl1]=ll;
                    split2(r1.z,hh,ll); bt_hi[nb][n1+2][kl1]=hh; bt_lo[nb][n1+2][kl1]=ll;
                    split2(r1.w,hh,ll); bt_hi[nb][n1+3][kl1]=hh; bt_lo[nb][n1+3][kl1]=ll;
                }
            }
            __syncthreads();
        }

        // ---- scatter q (scaled+bias), k, v^T into LDS from acc ----
        #pragma unroll
        for (int f = 0; f < 3; ++f) {
            int n = wn * 48 + f * 16 + (lane & 15);
            int m = n >> 5, d = n & 31;
            float bias = qkv_b[m * 384 + h * 32 + d];
            #pragma unroll
            for (int r = 0; r < 4; ++r) {
                int row = wm * 16 + (lane >> 4) * 4 + r;
                if (row < NP) {
                    float v = acc[f][r] + bias;
                    if (m == 0)      qs[row][d]  = v * SCALE;
                    else if (m == 1) kss[row][d] = v;
                    else             vst[d][row] = v;
                }
            }
        }
        __syncthreads();

        // ---- S = q k^T (fp32 VALU) ----
        if (tid < 338) {
            int tn2 = tid / 13, tm2 = tid % 13;
            int n0 = tn2 * 2, m0 = tm2 * 4;
            float s[2][4] = {};
            #pragma unroll
            for (int k = 0; k < 32; k += 4) {
                float4 qa[2], kb[4];
                #pragma unroll
                for (int i = 0; i < 2; ++i)
                    qa[i] = *reinterpret_cast<const float4*>(&qs[n0 + i][k]);
                #pragma unroll
                for (int j = 0; j < 4; ++j)
                    kb[j] = *reinterpret_cast<const float4*>(&kss[m0 + j][k]);
                #pragma unroll
                for (int i = 0; i < 2; ++i)
                    #pragma unroll
                    for (int j = 0; j < 4; ++j)
                        s[i][j] += qa[i].x * kb[j].x + qa[i].y * kb[j].y +
                                   qa[i].z * kb[j].z + qa[i].w * kb[j].w;
            }
            #pragma unroll
            for (int i = 0; i < 2; ++i)
                #pragma unroll
                for (int j = 0; j < 4; ++j)
                    at[n0 + i][m0 + j] = s[i][j];
        }
        __syncthreads();

        // ---- softmax + bias AFTER softmax ----
        {
            int wv2 = tid >> 6, lane64 = tid & 63;
            for (int r = wv2; r < NTOK; r += 8) {
                float v = (lane64 < NTOK) ? at[r][lane64] : -3.4e38f;
                float m = v;
                #pragma unroll
                for (int off = 32; off; off >>= 1) m = fmaxf(m, __shfl_xor(m, off));
                float e = (lane64 < NTOK) ? __expf(v - m) : 0.f;
                float ssum = e;
                #pragma unroll
                for (int off = 32; off; off >>= 1) ssum += __shfl_xor(ssum, off);
                if (lane64 < NP) {
                    float res = 0.f;
                    if (lane64 < NTOK) {
                        int py = r / 7, px = r % 7, qy = lane64 / 7, qx = lane64 % 7;
                        int bidx = (py - qy + 6) * 13 + (px - qx + 6);
                        res = e / ssum + rel_table[bidx * NH + h];
                    }
                    at[r][lane64] = res;
                }
            }
        }
        __syncthreads();

        // ---- out_h = attn @ v (fp32 VALU), contiguous float2 stores ----
        if (tid < 208) {
            int tn3 = tid / 16, td = tid % 16;
            int n0 = tn3 * 4, d0 = td * 2;
            float o[4][2] = {};
            #pragma unroll
            for (int m = 0; m < NP; m += 4) {
                float4 pa[4], vb[2];
                #pragma unroll
                for (int i = 0; i < 4; ++i)
                    pa[i] = *reinterpret_cast<const float4*>(&at[n0 + i][m]);
                #pragma unroll
                for (int j = 0; j < 2; ++j)
                    vb[j] = *reinterpret_cast<const float4*>(&vst[d0 + j][m]);
                #pragma unroll
                for (int i = 0; i < 4; ++i)
                    #pragma unroll
                    for (int j = 0; j < 2; ++j)
                        o[i][j] += pa[i].x * vb[j].x + pa[i].y * vb[j].y +
                                   pa[i].z * vb[j].z + pa[i].w * vb[j].w;
            }
            #pragma unroll
            for (int i = 0; i < 4; ++i) {
                int n = n0 + i;
                if (n < NTOK) {
                    int Y = wy * 7 + n / 7, X = wx * 7 + n % 7;
                    size_t base = (size_t)((bi * 56 + Y) * 56 + X) * DIM + h * 32 + d0;
                    *reinterpret_cast<float2*>(out + base) = make_float2(o[i][0], o[i][1]);
                }
            }
        }
        __syncthreads();
    }
}

// ---------------------------------------------------------------------------
// Kernel B: output projection via split-bf16 MFMA, IN PLACE on d_out.
// grid=784 (64 tokens each), block=512.
// ---------------------------------------------------------------------------
__global__ __launch_bounds__(512) void wmsa_proj_kernel(
    const float* __restrict__ proj_w, const float* __restrict__ proj_b,
    float* __restrict__ out)
{
    __shared__ __align__(16) u16 xs_hi[64][392];   // 50176 B
    __shared__ __align__(16) u16 xs_lo[64][392];   // 50176 B
    __shared__ __align__(16) u16 bt_hi[384][40];   // 30720 B
    __shared__ __align__(16) u16 bt_lo[384][40];   // 30720 B => 161792 B

    const int tid = threadIdx.x, lane = tid & 63, wv = tid >> 6;
    const int wm = wv >> 1, wn = wv & 1;
    const size_t tok0 = (size_t)blockIdx.x * 64;

    // stage A = 64 token rows of out -> hi/lo
    for (int i = tid; i < 64 * 96; i += 512) {
        int n = i / 96, c4 = i % 96;
        float4 v = reinterpret_cast<const float4*>(out + (tok0 + n) * DIM)[c4];
        u16 h0,l0,h1,l1,h2,l2,h3,l3;
        split2(v.x,h0,l0); split2(v.y,h1,l1); split2(v.z,h2,l2); split2(v.w,h3,l3);
        int c = c4 * 4;
        xs_hi[n][c]=h0; xs_hi[n][c+1]=h1; xs_hi[n][c+2]=h2; xs_hi[n][c+3]=h3;
        xs_lo[n][c]=l0; xs_lo[n][c+1]=l1; xs_lo[n][c+2]=l2; xs_lo[n][c+3]=l3;
    }

    f32x4 acc[12];
    #pragma unroll
    for (int f = 0; f < 12; ++f) { acc[f][0]=0.f; acc[f][1]=0.f; acc[f][2]=0.f; acc[f][3]=0.f; }

    const int arow = wm * 16 + (lane & 15);
    const int koff = (lane >> 4) * 8;

    // chunk: 32 k-rows x 384 cols = 3072 float4, 6 per thread (f = tid + j*512)
    float4 rr[6];
    #pragma unroll
    for (int j = 0; j < 6; ++j) {
        int f = tid + j * 512, kl = f / 96, c4 = f % 96;
        rr[j] = reinterpret_cast<const float4*>(proj_w + (size_t)kl * 384 + c4 * 4)[0];
    }

    for (int ksi = 0; ksi < 12; ++ksi) {
        __syncthreads();   // prev MFMA done reading bt (and 1st iter: xs staged)
        #pragma unroll
        for (int j = 0; j < 6; ++j) {
            int f = tid + j * 512, kl = f / 96, c4 = f % 96, n0 = c4 * 4;
            u16 hh, ll;
            split2(rr[j].x,hh,ll); bt_hi[n0  ][kl]=hh; bt_lo[n0  ][kl]=ll;
            split2(rr[j].y,hh,ll); bt_hi[n0+1][kl]=hh; bt_lo[n0+1][kl]=ll;
            split2(rr[j].z,hh,ll); bt_hi[n0+2][kl]=hh; bt_lo[n0+2][kl]=ll;
            split2(rr[j].w,hh,ll); bt_hi[n0+3][kl]=hh; bt_lo[n0+3][kl]=ll;
        }
        __syncthreads();
        if (ksi < 11) {
            int kg = (ksi + 1) * 32;
            #pragma unroll
            for (int j = 0; j < 6; ++j) {
                int f = tid + j * 512, kl = f / 96, c4 = f % 96;
                rr[j] = reinterpret_cast<const float4*>(
                            proj_w + (size_t)(kg + kl) * 384 + c4 * 4)[0];
            }
        }
        bf16x8 ah = *reinterpret_cast<const bf16x8*>(&xs_hi[arow][ksi * 32 + koff]);
        bf16x8 al = *reinterpret_cast<const bf16x8*>(&xs_lo[arow][ksi * 32 + koff]);
        #pragma unroll
        for (int f = 0; f < 12; ++f) {
            int n = wn * 192 + f * 16 + (lane & 15);
            bf16x8 bh = *reinterpret_cast<const bf16x8*>(&bt_hi[n][koff]);
            bf16x8 bl = *reinterpret_cast<const bf16x8*>(&bt_lo[n][koff]);
            acc[f] = __builtin_amdgcn_mfma_f32_16x16x32_bf16(ah, bh, acc[f], 0, 0, 0);
            acc[f] = __builtin_amdgcn_mfma_f32_16x16x32_bf16(ah, bl, acc[f], 0, 0, 0);
            acc[f] = __builtin_amdgcn_mfma_f32_16x16x32_bf16(al, bh, acc[f], 0, 0, 0);
        }
    }

    // epilogue: C layout col=lane&15, row=(lane>>4)*4+r  (HW-verified m89)
    #pragma unroll
    for (int f = 0; f < 12; ++f) {
        int n = wn * 192 + f * 16 + (lane & 15);
        float pb = proj_b[n];
        #pragma unroll
        for (int r = 0; r < 4; ++r) {
            int row = wm * 16 + (lane >> 4) * 4 + r;
            out[(tok0 + row) * DIM + n] = acc[f][r] + pb;
        }
    }
}

extern "C" void kernel_launch(void* const* d_in, const int* in_sizes, int n_in,
                              void* d_out, int out_size, void* d_ws, size_t ws_size,
                              hipStream_t stream) {
    const float* x         = (const float*)d_in[0];
    const float* qkv_w     = (const float*)d_in[1];
    const float* qkv_b     = (const float*)d_in[2];
    const float* proj_w    = (const float*)d_in[3];
    const float* proj_b    = (const float*)d_in[4];
    const float* rel_table = (const float*)d_in[5];
    float* out = (float*)d_out;

    hipLaunchKernelGGL(wmsa_attn_kernel, dim3(1024), dim3(512), 0, stream,
                       x, qkv_w, qkv_b, rel_table, out);
    hipLaunchKernelGGL(wmsa_proj_kernel, dim3(784), dim3(512), 0, stream,
                       proj_w, proj_b, out);
}